// Round 3
// baseline (382.673 us; speedup 1.0000x reference)
//
#include <hip/hip_runtime.h>
#include <stdint.h>

// Problem dims
#define B_SZ   512
#define NIN    2048
#define UNITS  4096
#define KTOT   (NIN + UNITS)
// GEMM tiling
#define BM     64
#define BN     128
#define BK     32
#define BSTR   36   // B-LDS row stride (shorts): 72B rows, 8B aligned -> conflict-free b64 frag reads

typedef __attribute__((ext_vector_type(8))) __bf16        bf16x8;
typedef __attribute__((ext_vector_type(4))) float         f32x4;
typedef __attribute__((ext_vector_type(4))) unsigned int  u32x4;

__device__ __forceinline__ float bf2f(unsigned int h) {
    unsigned int u = h << 16;
    float f;
    __builtin_memcpy(&f, &u, 4);
    return f;
}
__device__ __forceinline__ unsigned int f2bf(float f) {
    unsigned int u;
    __builtin_memcpy(&u, &f, 4);
    return (u + 0x7fffu + ((u >> 16) & 1u)) >> 16;   // RNE; inputs finite, no NaN
}
// fp32 -> bf16 hi + bf16 lo (residual). hi+lo captures f to ~2^-18 relative.
__device__ __forceinline__ void split2(float f, unsigned int& hi, unsigned int& lo) {
    hi = f2bf(f);
    lo = f2bf(f - bf2f(hi));
}

__device__ __forceinline__ void adex_one(float it, float v, float w, float z, int r,
                                         float& nv, float& nz, float& nw, float& nr)
{
    const float EL = -70.6f, THR = -50.4f;
    const float dt_gl_c    = (float)(30.0 / 281.0);
    const float dt_gl_c_dt = (float)(60.0 / 281.0);
    const float dt_tauw    = (float)(1.0 / 144.0);
    const float dt_a_tauw  = (float)(4.0 / 144.0);
    float ex = expf((v - THR) * 0.5f);
    ex = fminf(ex, 281.0f);                          // clip upper = 30/DT_GL_C; exp>=0 so lower clip moot
    float vv = v - dt_gl_c * (v - EL) + dt_gl_c_dt * ex + (it - w) / 281.0f;
    if (z > 0.5f) vv = -70.6f;                       // reset after spike
    nv = vv;
    nw = w - dt_tauw * w + dt_a_tauw * (v - EL) + 0.0805f * z;
    float s = (vv > THR) ? 1.0f : 0.0f;              // v_scaled>0 <=> new_v>THR (THR-EL>0)
    if (r > 0) s = 0.0f;                             // refractory
    nz = s;
    int ri = r - 1 + (s > 0.5f ? 2 : 0);
    ri = ri < 0 ? 0 : (ri > 2 ? 2 : ri);
    nr = (float)ri;
}

// ---------------------------------------------------------------------------
// Fused AdEx step. i_t = [inputs | z] @ [Win ; Wrec], fp32 inputs, split-bf16
// MFMA (hi*hi + hi*lo + lo*hi), fp32 accumulate; AdEx dynamics in-register.
// Grid (32, 8) = 256 blocks, 256 threads (4 waves 2x2; wave = 32m x 64n).
// ---------------------------------------------------------------------------
__global__ __launch_bounds__(256)
void adex_fused(const float* __restrict__ inp,
                const float* __restrict__ zsp,
                const float* __restrict__ Win,
                const float* __restrict__ Wrec,
                const float* __restrict__ v_in,
                const float* __restrict__ w_in,
                const int*   __restrict__ r_in,
                float*       __restrict__ out)
{
    __shared__ unsigned short Ah[BM * BK];      // 4 KB, [m][k], 16B chunks XOR-swizzled
    __shared__ unsigned short Al[BM * BK];      // 4 KB
    __shared__ unsigned short Bh[BN * BSTR];    // 9 KB, [n][k] stride 36
    __shared__ unsigned short Bl[BN * BSTR];    // 9 KB

    const int tid = threadIdx.x;
    const int l   = tid & 63;
    const int w   = tid >> 6;           // wave 0..3
    const int lm  = l & 15;
    const int q   = l >> 4;
    const int bn0 = blockIdx.x * BN;
    const int bm0 = blockIdx.y * BM;
    const int wm  = (w >> 1) * 32;      // wave row offset
    const int wn  = (w & 1) * 64;       // wave col offset

    // A staging: thread t owns logical 16B-bf16 chunk (row am, chunk ac);
    // physical chunk = ac ^ ((am>>1)&3)  -> frag ds_read_b128 is 2-way max (free).
    const int am = tid >> 2;            // 0..63
    const int ac = tid & 3;             // 0..3
    const int as_off = am * BK + ((ac ^ ((am >> 1) & 3)) * 8);   // shorts

    // B staging: thread t owns W rows kk,kk+1 at cols nn..nn+7 (transpose-pack)
    const int kk = (tid >> 4) * 2;      // 0..30
    const int nn = (tid & 15) * 8;      // 0..120

    f32x4 acc[2][4];
    const f32x4 zero4 = {0.f, 0.f, 0.f, 0.f};
    #pragma unroll
    for (int i = 0; i < 2; ++i)
        #pragma unroll
        for (int j = 0; j < 4; ++j) acc[i][j] = zero4;

    // prefetch k0 = 0 (inputs / Win region)
    const float* ap0 = inp + (size_t)(bm0 + am) * NIN + ac * 8;
    float4 aR0 = *(const float4*)ap0;
    float4 aR1 = *(const float4*)(ap0 + 4);
    const float* bp0 = Win + (size_t)kk * UNITS + bn0 + nn;
    float4 b0a = *(const float4*)bp0;
    float4 b0b = *(const float4*)(bp0 + 4);
    float4 b1a = *(const float4*)(bp0 + UNITS);
    float4 b1b = *(const float4*)(bp0 + UNITS + 4);

    for (int k0 = 0; k0 < KTOT; k0 += BK) {
        // --- convert + store prefetched tile to LDS ---
        {
            const float av[8] = {aR0.x, aR0.y, aR0.z, aR0.w, aR1.x, aR1.y, aR1.z, aR1.w};
            unsigned int h[8], lo[8];
            #pragma unroll
            for (int c = 0; c < 8; ++c) split2(av[c], h[c], lo[c]);
            u32x4 H = { h[0] | (h[1] << 16),  h[2] | (h[3] << 16),
                        h[4] | (h[5] << 16),  h[6] | (h[7] << 16) };
            u32x4 L = { lo[0] | (lo[1] << 16), lo[2] | (lo[3] << 16),
                        lo[4] | (lo[5] << 16), lo[6] | (lo[7] << 16) };
            *(u32x4*)(Ah + as_off) = H;
            *(u32x4*)(Al + as_off) = L;
        }
        {
            const float r0[8] = {b0a.x, b0a.y, b0a.z, b0a.w, b0b.x, b0b.y, b0b.z, b0b.w};
            const float r1[8] = {b1a.x, b1a.y, b1a.z, b1a.w, b1b.x, b1b.y, b1b.z, b1b.w};
            unsigned short* bh = Bh + nn * BSTR + kk;
            unsigned short* bl = Bl + nn * BSTR + kk;
            #pragma unroll
            for (int c = 0; c < 8; ++c) {
                unsigned int h0, l0, h1, l1;
                split2(r0[c], h0, l0);
                split2(r1[c], h1, l1);
                *(unsigned int*)(bh + c * BSTR) = h0 | (h1 << 16);
                *(unsigned int*)(bl + c * BSTR) = l0 | (l1 << 16);
            }
        }
        __syncthreads();

        // --- issue next tile's global loads (latency overlaps MFMA below) ---
        float4 aN0 = aR0, aN1 = aR1, c0a = b0a, c0b = b0b, c1a = b1a, c1b = b1b;
        const int k1 = k0 + BK;
        if (k1 < KTOT) {
            const float* ar; size_t astr; const float* wr;
            if (k1 < NIN) { ar = inp + k1;         astr = NIN;   wr = Win  + (size_t)k1 * UNITS; }
            else          { ar = zsp + (k1 - NIN); astr = UNITS; wr = Wrec + (size_t)(k1 - NIN) * UNITS; }
            const float* ap = ar + (size_t)(bm0 + am) * astr + ac * 8;
            aN0 = *(const float4*)ap;
            aN1 = *(const float4*)(ap + 4);
            const float* bp = wr + (size_t)kk * UNITS + bn0 + nn;
            c0a = *(const float4*)bp;
            c0b = *(const float4*)(bp + 4);
            c1a = *(const float4*)(bp + UNITS);
            c1b = *(const float4*)(bp + UNITS + 4);
        }

        // --- fragments + 24 MFMA per wave ---
        bf16x8 ah[2], al_[2], bh[4], blo[4];
        #pragma unroll
        for (int i = 0; i < 2; ++i) {
            const int m   = wm + i * 16 + lm;
            const int off = m * BK + ((q ^ ((lm >> 1) & 3)) * 8);
            ah[i]  = *(const bf16x8*)(Ah + off);           // ds_read_b128
            al_[i] = *(const bf16x8*)(Al + off);
        }
        #pragma unroll
        for (int j = 0; j < 4; ++j) {
            const int off = (wn + j * 16 + lm) * BSTR + q * 8;   // 8B aligned
            const uint2 h2a = *(const uint2*)(Bh + off);
            const uint2 h2b = *(const uint2*)(Bh + off + 4);
            const uint2 l2a = *(const uint2*)(Bl + off);
            const uint2 l2b = *(const uint2*)(Bl + off + 4);
            u32x4 hu = { h2a.x, h2a.y, h2b.x, h2b.y };
            u32x4 lu = { l2a.x, l2a.y, l2b.x, l2b.y };
            bh[j]  = __builtin_bit_cast(bf16x8, hu);
            blo[j] = __builtin_bit_cast(bf16x8, lu);
        }
        #pragma unroll
        for (int i = 0; i < 2; ++i)
            #pragma unroll
            for (int j = 0; j < 4; ++j) {
                acc[i][j] = __builtin_amdgcn_mfma_f32_16x16x32_bf16(ah[i],  bh[j],  acc[i][j], 0, 0, 0);
                acc[i][j] = __builtin_amdgcn_mfma_f32_16x16x32_bf16(ah[i],  blo[j], acc[i][j], 0, 0, 0);
                acc[i][j] = __builtin_amdgcn_mfma_f32_16x16x32_bf16(al_[i], bh[j],  acc[i][j], 0, 0, 0);
            }

        __syncthreads();
        aR0 = aN0; aR1 = aN1; b0a = c0a; b0b = c0b; b1a = c1a; b1b = c1b;
    }

    // --- fused AdEx epilogue. C/D layout: col=lane&15, row=(lane>>4)*4+reg ---
    const size_t CH = (size_t)B_SZ * UNITS;
    float dgv[4];
    #pragma unroll
    for (int j = 0; j < 4; ++j) {
        const int n = bn0 + wn + j * 16 + lm;
        dgv[j] = Wrec[(size_t)n * UNITS + n];      // autapse diagonal (exact fp32)
    }
    #pragma unroll
    for (int i = 0; i < 2; ++i) {
        #pragma unroll
        for (int rr = 0; rr < 4; ++rr) {
            const int b = bm0 + wm + i * 16 + q * 4 + rr;
            const size_t rowb = (size_t)b * UNITS;
            #pragma unroll
            for (int j = 0; j < 4; ++j) {
                const int n = bn0 + wn + j * 16 + lm;
                const size_t idx = rowb + n;
                const float vv = v_in[idx];
                const float wv = w_in[idx];
                const float zv = zsp[idx];
                const int   rv = r_in[idx];
                const float it = acc[i][j][rr] - zv * dgv[j];
                float nv, nz, nw, nr;
                adex_one(it, vv, wv, zv, rv, nv, nz, nw, nr);
                out[idx]          = nv;
                out[CH + idx]     = nz;
                out[2 * CH + idx] = nw;
                out[3 * CH + idx] = nr;
            }
        }
    }
}

// ---------------------------------------------------------------------------
// d_in order (setup_inputs dict): inputs, v, r(int32), w, z, input_weights, recurrent_weights
// ---------------------------------------------------------------------------
extern "C" void kernel_launch(void* const* d_in, const int* in_sizes, int n_in,
                              void* d_out, int out_size, void* d_ws, size_t ws_size,
                              hipStream_t stream) {
    (void)in_sizes; (void)n_in; (void)out_size; (void)d_ws; (void)ws_size;
    const float* inp  = (const float*)d_in[0];
    const float* v    = (const float*)d_in[1];
    const int*   r    = (const int*)d_in[2];
    const float* w    = (const float*)d_in[3];
    const float* z    = (const float*)d_in[4];
    const float* Win  = (const float*)d_in[5];
    const float* Wrec = (const float*)d_in[6];
    float* out = (float*)d_out;

    dim3 g(UNITS / BN, B_SZ / BM);   // (32, 8) = 256 blocks
    adex_fused<<<g, dim3(256), 0, stream>>>(inp, z, Win, Wrec, v, w, r, out);
}

// Round 4
// 377.395 us; speedup vs baseline: 1.0140x; 1.0140x over previous
//
#include <hip/hip_runtime.h>
#include <stdint.h>

// Problem dims
#define B_SZ   512
#define NIN    2048
#define UNITS  4096
#define KTOT   (NIN + UNITS)
// GEMM tiling
#define BM     32
#define BN     128
#define BK     32
#define BSTR   36   // B-LDS row stride (shorts): 72B rows, 8B-aligned b64 frag reads

typedef __attribute__((ext_vector_type(8))) __bf16        bf16x8;
typedef __attribute__((ext_vector_type(4))) float         f32x4;

__device__ __forceinline__ unsigned int fbits(float f) {
    unsigned int u; __builtin_memcpy(&u, &f, 4); return u;
}
__device__ __forceinline__ float tof(unsigned int u) {
    float f; __builtin_memcpy(&f, &u, 4); return f;
}

__device__ __forceinline__ void adex_one(float it, float v, float w, float z, int r,
                                         float& nv, float& nz, float& nw, float& nr)
{
    const float EL = -70.6f, THR = -50.4f;
    const float dt_gl_c    = (float)(30.0 / 281.0);
    const float dt_gl_c_dt = (float)(60.0 / 281.0);
    const float dt_tauw    = (float)(1.0 / 144.0);
    const float dt_a_tauw  = (float)(4.0 / 144.0);
    float ex = expf((v - THR) * 0.5f);
    ex = fminf(ex, 281.0f);                          // clip upper = 30/DT_GL_C
    float vv = v - dt_gl_c * (v - EL) + dt_gl_c_dt * ex + (it - w) / 281.0f;
    if (z > 0.5f) vv = -70.6f;                       // reset after spike
    nv = vv;
    nw = w - dt_tauw * w + dt_a_tauw * (v - EL) + 0.0805f * z;
    float s = (vv > THR) ? 1.0f : 0.0f;              // v_scaled>0 <=> new_v>THR
    if (r > 0) s = 0.0f;                             // refractory
    nz = s;
    int ri = r - 1 + (s > 0.5f ? 2 : 0);
    ri = ri < 0 ? 0 : (ri > 2 ? 2 : ri);
    nr = (float)ri;
}

// ---------------------------------------------------------------------------
// Fused AdEx step. i_t = [inputs | z] @ [Win ; Wrec], fp32 in, split-bf16 MFMA.
// Win region (k<2048): 3 passes (ah·bh + ah·bl + al·bh).
// Wrec region: z is exact in bf16 -> al = 0 -> 2 passes, no Al staging.
// Grid (32,16)=512 blocks -> 2 blocks/CU; 256 thr (4 waves 2x2; wave=16m x 64n).
// ---------------------------------------------------------------------------
__global__ __launch_bounds__(256, 2)
void adex_fused(const float* __restrict__ inp,
                const float* __restrict__ zsp,
                const float* __restrict__ Win,
                const float* __restrict__ Wrec,
                const float* __restrict__ v_in,
                const float* __restrict__ w_in,
                const int*   __restrict__ r_in,
                float*       __restrict__ out)
{
    __shared__ unsigned short Ah[BM * BK];      // 2 KB  [m][k]
    __shared__ unsigned short Al[BM * BK];      // 2 KB
    __shared__ unsigned short Bh[BN * BSTR];    // 9 KB  [n][k] stride 36
    __shared__ unsigned short Bl[BN * BSTR];    // 9 KB

    const int tid = threadIdx.x;
    const int l   = tid & 63;
    const int w   = tid >> 6;           // wave 0..3
    const int lm  = l & 15;
    const int q   = l >> 4;
    const int bn0 = blockIdx.x * BN;
    const int bm0 = blockIdx.y * BM;
    const int wm  = (w >> 1) * 16;      // wave row offset
    const int wn  = (w & 1) * 64;       // wave col offset

    // A staging: thread -> (row ar 0..31, k-quad kq 0..7), one float4
    const int ar = tid >> 3;
    const int kq = tid & 7;
    // B staging: k-major lanes: k-pair bkk = 2*(tid&15), n-oct bnn = 8*(tid>>4)
    // -> b32 LDS writes land 2-way max (bank = 16*((l>>4)&1) + (l&15) + 18c)
    const int bkk = 2 * (tid & 15);
    const int bnn = 8 * (tid >> 4);

    f32x4 acc[4];
    const f32x4 zero4 = {0.f, 0.f, 0.f, 0.f};
    #pragma unroll
    for (int j = 0; j < 4; ++j) acc[j] = zero4;

    // prefetch k0 = 0 (inputs / Win region)
    float4 aR = *(const float4*)(inp + (size_t)(bm0 + ar) * NIN + kq * 4);
    const float* bp0 = Win + (size_t)bkk * UNITS + bn0 + bnn;
    float4 b0a = *(const float4*)bp0;
    float4 b0b = *(const float4*)(bp0 + 4);
    float4 b1a = *(const float4*)(bp0 + UNITS);
    float4 b1b = *(const float4*)(bp0 + UNITS + 4);

    for (int k0 = 0; k0 < KTOT; k0 += BK) {
        const bool full = (k0 < NIN);   // A needs lo split only in inputs region

        // --- A tile: truncation split, hi always, lo only if full ---
        {
            const unsigned int u0 = fbits(aR.x), u1 = fbits(aR.y),
                               u2 = fbits(aR.z), u3 = fbits(aR.w);
            uint2 H = { (u0 >> 16) | (u1 & 0xffff0000u),
                        (u2 >> 16) | (u3 & 0xffff0000u) };
            *(uint2*)(Ah + ar * BK + kq * 4) = H;
            if (full) {
                const float h0 = tof(u0 & 0xffff0000u), h1 = tof(u1 & 0xffff0000u);
                const float h2 = tof(u2 & 0xffff0000u), h3 = tof(u3 & 0xffff0000u);
                const unsigned int l0 = fbits(aR.x - h0), l1 = fbits(aR.y - h1);
                const unsigned int l2 = fbits(aR.z - h2), l3 = fbits(aR.w - h3);
                uint2 L = { (l0 >> 16) | (l1 & 0xffff0000u),
                            (l2 >> 16) | (l3 & 0xffff0000u) };
                *(uint2*)(Al + ar * BK + kq * 4) = L;
            }
        }
        // --- B tile: k-pair pack, conflict-free b32 writes ---
        {
            const float r0[8] = {b0a.x, b0a.y, b0a.z, b0a.w, b0b.x, b0b.y, b0b.z, b0b.w};
            const float r1[8] = {b1a.x, b1a.y, b1a.z, b1a.w, b1b.x, b1b.y, b1b.z, b1b.w};
            #pragma unroll
            for (int c = 0; c < 8; ++c) {
                const unsigned int u_0 = fbits(r0[c]), u_1 = fbits(r1[c]);
                *(unsigned int*)(Bh + (bnn + c) * BSTR + bkk) =
                    (u_0 >> 16) | (u_1 & 0xffff0000u);
                const float h0 = tof(u_0 & 0xffff0000u), h1 = tof(u_1 & 0xffff0000u);
                const unsigned int l_0 = fbits(r0[c] - h0), l_1 = fbits(r1[c] - h1);
                *(unsigned int*)(Bl + (bnn + c) * BSTR + bkk) =
                    (l_0 >> 16) | (l_1 & 0xffff0000u);
            }
        }
        __syncthreads();

        // --- issue next tile's global loads (overlap MFMA below) ---
        float4 aN = aR, c0a = b0a, c0b = b0b, c1a = b1a, c1b = b1b;
        const int k1 = k0 + BK;
        if (k1 < KTOT) {
            const float* arp; size_t astr; const float* wr;
            if (k1 < NIN) { arp = inp + k1;         astr = NIN;   wr = Win  + (size_t)k1 * UNITS; }
            else          { arp = zsp + (k1 - NIN); astr = UNITS; wr = Wrec + (size_t)(k1 - NIN) * UNITS; }
            aN = *(const float4*)(arp + (size_t)(bm0 + ar) * astr + kq * 4);
            const float* bp = wr + (size_t)bkk * UNITS + bn0 + bnn;
            c0a = *(const float4*)bp;
            c0b = *(const float4*)(bp + 4);
            c1a = *(const float4*)(bp + UNITS);
            c1b = *(const float4*)(bp + UNITS + 4);
        }

        // --- fragments + MFMA (8 or 12 per wave) ---
        bf16x8 ah_, al_ = {};
        {
            const int off = (wm + lm) * BK + q * 8;
            ah_ = *(const bf16x8*)(Ah + off);              // ds_read_b128
            if (full) al_ = *(const bf16x8*)(Al + off);
        }
        bf16x8 bh_[4], bl_[4];
        #pragma unroll
        for (int j = 0; j < 4; ++j) {
            const int off = (wn + j * 16 + lm) * BSTR + q * 8;   // 8B aligned
            const uint2 ha = *(const uint2*)(Bh + off);
            const uint2 hb = *(const uint2*)(Bh + off + 4);
            const uint2 la = *(const uint2*)(Bl + off);
            const uint2 lb = *(const uint2*)(Bl + off + 4);
            uint4 hu = { ha.x, ha.y, hb.x, hb.y };
            uint4 lu = { la.x, la.y, lb.x, lb.y };
            bh_[j] = __builtin_bit_cast(bf16x8, hu);
            bl_[j] = __builtin_bit_cast(bf16x8, lu);
        }
        #pragma unroll
        for (int j = 0; j < 4; ++j) {
            acc[j] = __builtin_amdgcn_mfma_f32_16x16x32_bf16(ah_, bh_[j], acc[j], 0, 0, 0);
            acc[j] = __builtin_amdgcn_mfma_f32_16x16x32_bf16(ah_, bl_[j], acc[j], 0, 0, 0);
        }
        if (full) {
            #pragma unroll
            for (int j = 0; j < 4; ++j)
                acc[j] = __builtin_amdgcn_mfma_f32_16x16x32_bf16(al_, bh_[j], acc[j], 0, 0, 0);
        }

        __syncthreads();
        aR = aN; b0a = c0a; b0b = c0b; b1a = c1a; b1b = c1b;
    }

    // --- fused AdEx epilogue. C/D layout: col=lane&15, row=(lane>>4)*4+reg ---
    const size_t CH = (size_t)B_SZ * UNITS;
    float dgv[4];
    #pragma unroll
    for (int j = 0; j < 4; ++j) {
        const int n = bn0 + wn + j * 16 + lm;
        dgv[j] = Wrec[(size_t)n * UNITS + n];      // autapse diagonal
    }
    #pragma unroll
    for (int rr = 0; rr < 4; ++rr) {
        const int b = bm0 + wm + q * 4 + rr;
        const size_t rowb = (size_t)b * UNITS;
        #pragma unroll
        for (int j = 0; j < 4; ++j) {
            const int n = bn0 + wn + j * 16 + lm;
            const size_t idx = rowb + n;
            const float vv = v_in[idx];
            const float wv = w_in[idx];
            const float zv = zsp[idx];
            const int   rv = r_in[idx];
            const float it = acc[j][rr] - zv * dgv[j];
            float nv, nz, nw, nr;
            adex_one(it, vv, wv, zv, rv, nv, nz, nw, nr);
            out[idx]          = nv;
            out[CH + idx]     = nz;
            out[2 * CH + idx] = nw;
            out[3 * CH + idx] = nr;
        }
    }
}

// ---------------------------------------------------------------------------
// d_in order (setup_inputs dict): inputs, v, r(int32), w, z, input_weights, recurrent_weights
// ---------------------------------------------------------------------------
extern "C" void kernel_launch(void* const* d_in, const int* in_sizes, int n_in,
                              void* d_out, int out_size, void* d_ws, size_t ws_size,
                              hipStream_t stream) {
    (void)in_sizes; (void)n_in; (void)out_size; (void)d_ws; (void)ws_size;
    const float* inp  = (const float*)d_in[0];
    const float* v    = (const float*)d_in[1];
    const int*   r    = (const int*)d_in[2];
    const float* w    = (const float*)d_in[3];
    const float* z    = (const float*)d_in[4];
    const float* Win  = (const float*)d_in[5];
    const float* Wrec = (const float*)d_in[6];
    float* out = (float*)d_out;

    dim3 g(UNITS / BN, B_SZ / BM);   // (32, 16) = 512 blocks -> 2 per CU
    adex_fused<<<g, dim3(256), 0, stream>>>(inp, z, Win, Wrec, v, w, r, out);
}

// Round 6
// 362.558 us; speedup vs baseline: 1.0555x; 1.0409x over previous
//
#include <hip/hip_runtime.h>
#include <stdint.h>

// Problem dims
#define B_SZ   512
#define NIN    2048
#define UNITS  4096
#define KTOT   (NIN + UNITS)
// GEMM tiling
#define BM     32
#define BN     128
#define BK     32
#define BSTR   36   // B-LDS row stride (shorts): 72B rows, 8B-aligned b64 frag reads

typedef __attribute__((ext_vector_type(8))) __bf16        bf16x8;
typedef __attribute__((ext_vector_type(4))) float         f32x4;

__device__ __forceinline__ unsigned int fbits(float f) {
    unsigned int u; __builtin_memcpy(&u, &f, 4); return u;
}
__device__ __forceinline__ float tof(unsigned int u) {
    float f; __builtin_memcpy(&f, &u, 4); return f;
}

// Barrier with LDS-visibility only: does NOT drain vmcnt, so global prefetch
// loads stay in flight across it (legal here: staging is global->reg->LDS;
// cross-wave visibility needs only lgkmcnt(0)). __syncthreads() would emit
// s_waitcnt vmcnt(0) and serialize every iteration on load latency.
__device__ __forceinline__ void lds_barrier() {
    asm volatile("s_waitcnt lgkmcnt(0)\n\ts_barrier" ::: "memory");
}

__device__ __forceinline__ void adex_one(float it, float v, float w, float z, int r,
                                         float& nv, float& nz, float& nw, float& nr)
{
    const float EL = -70.6f, THR = -50.4f;
    const float dt_gl_c    = (float)(30.0 / 281.0);
    const float dt_gl_c_dt = (float)(60.0 / 281.0);
    const float dt_tauw    = (float)(1.0 / 144.0);
    const float dt_a_tauw  = (float)(4.0 / 144.0);
    float ex = expf((v - THR) * 0.5f);
    ex = fminf(ex, 281.0f);                          // clip upper = 30/DT_GL_C
    float vv = v - dt_gl_c * (v - EL) + dt_gl_c_dt * ex + (it - w) / 281.0f;
    if (z > 0.5f) vv = -70.6f;                       // reset after spike
    nv = vv;
    nw = w - dt_tauw * w + dt_a_tauw * (v - EL) + 0.0805f * z;
    float s = (vv > THR) ? 1.0f : 0.0f;              // v_scaled>0 <=> new_v>THR
    if (r > 0) s = 0.0f;                             // refractory
    nz = s;
    int ri = r - 1 + (s > 0.5f ? 2 : 0);
    ri = ri < 0 ? 0 : (ri > 2 ? 2 : ri);
    nr = (float)ri;
}

// ---------------------------------------------------------------------------
// Fused AdEx step. i_t = [inputs | z] @ [Win ; Wrec], fp32 in, split-bf16 MFMA.
// Win region (k<2048): 3 passes (ah·bh + ah·bl + al·bh); Wrec region: z exact
// in bf16 -> 2 passes. Depth-2 register pipeline + lgkm-only barriers: global
// loads issued 2 iterations ahead of use, never drained by a barrier.
// Grid (32,16)=512 blocks -> 2/CU; 256 thr (4 waves 2x2; wave=16m x 64n).
// ---------------------------------------------------------------------------
__global__ __launch_bounds__(256, 2)
void adex_fused(const float* __restrict__ inp,
                const float* __restrict__ zsp,
                const float* __restrict__ Win,
                const float* __restrict__ Wrec,
                const float* __restrict__ v_in,
                const float* __restrict__ w_in,
                const int*   __restrict__ r_in,
                float*       __restrict__ out)
{
    __shared__ unsigned short Ah[BM * BK];      // 2 KB  [m][k]
    __shared__ unsigned short Al[BM * BK];      // 2 KB
    __shared__ unsigned short Bh[BN * BSTR];    // 9 KB  [n][k] stride 36
    __shared__ unsigned short Bl[BN * BSTR];    // 9 KB

    const int tid = threadIdx.x;
    const int l   = tid & 63;
    const int w   = tid >> 6;           // wave 0..3
    const int lm  = l & 15;
    const int q   = l >> 4;
    const int bn0 = blockIdx.x * BN;
    const int bm0 = blockIdx.y * BM;
    const int wm  = (w >> 1) * 16;      // wave row offset
    const int wn  = (w & 1) * 64;      // wave col offset

    // A staging: thread -> (row ar 0..31, k-quad kq 0..7), one float4
    const int ar = tid >> 3;
    const int kq = tid & 7;
    // B staging: k-major lanes: k-pair bkk=2*(tid&15), n-oct bnn=8*(tid>>4)
    // -> b32 LDS writes 2-way max (free)
    const int bkk = 2 * (tid & 15);
    const int bnn = 8 * (tid >> 4);

    // loop-invariant global bases
    const float* pAin = inp + (size_t)(bm0 + ar) * NIN   + kq * 4;
    const float* pAz  = zsp + (size_t)(bm0 + ar) * UNITS + kq * 4;
    const float* pBin = Win  + (size_t)bkk * UNITS + bn0 + bnn;
    const float* pBrc = Wrec + (size_t)bkk * UNITS + bn0 + bnn;

    f32x4 acc[4];
    const f32x4 zero4 = {0.f, 0.f, 0.f, 0.f};
    #pragma unroll
    for (int j = 0; j < 4; ++j) acc[j] = zero4;

    // preload pipeline slots: k=0 and k=32 (both in Win region)
    float4 aS0 = *(const float4*)(pAin);
    float4 aS1 = *(const float4*)(pAin + 32);
    float4 s0b0a = *(const float4*)(pBin);
    float4 s0b0b = *(const float4*)(pBin + 4);
    float4 s0b1a = *(const float4*)(pBin + UNITS);
    float4 s0b1b = *(const float4*)(pBin + UNITS + 4);
    const float* pB32 = pBin + (size_t)32 * UNITS;
    float4 s1b0a = *(const float4*)(pB32);
    float4 s1b0b = *(const float4*)(pB32 + 4);
    float4 s1b1a = *(const float4*)(pB32 + UNITS);
    float4 s1b1b = *(const float4*)(pB32 + UNITS + 4);

    auto tile = [&](float4& aT, float4& c0a, float4& c0b, float4& c1a, float4& c1b,
                    int k0) {
        const bool full = (k0 < NIN);   // A-lo only needed in inputs region

        // --- A tile: truncation split hi (+ lo if full) ---
        {
            const unsigned int u0 = fbits(aT.x), u1 = fbits(aT.y),
                               u2 = fbits(aT.z), u3 = fbits(aT.w);
            uint2 H = { (u0 >> 16) | (u1 & 0xffff0000u),
                        (u2 >> 16) | (u3 & 0xffff0000u) };
            *(uint2*)(Ah + ar * BK + kq * 4) = H;
            if (full) {
                const float h0 = tof(u0 & 0xffff0000u), h1 = tof(u1 & 0xffff0000u);
                const float h2 = tof(u2 & 0xffff0000u), h3 = tof(u3 & 0xffff0000u);
                const unsigned int l0 = fbits(aT.x - h0), l1 = fbits(aT.y - h1);
                const unsigned int l2 = fbits(aT.z - h2), l3 = fbits(aT.w - h3);
                uint2 L = { (l0 >> 16) | (l1 & 0xffff0000u),
                            (l2 >> 16) | (l3 & 0xffff0000u) };
                *(uint2*)(Al + ar * BK + kq * 4) = L;
            }
        }
        // --- B tile: k-pair pack, conflict-free b32 writes ---
        {
            const float r0[8] = {c0a.x, c0a.y, c0a.z, c0a.w, c0b.x, c0b.y, c0b.z, c0b.w};
            const float r1[8] = {c1a.x, c1a.y, c1a.z, c1a.w, c1b.x, c1b.y, c1b.z, c1b.w};
            #pragma unroll
            for (int c = 0; c < 8; ++c) {
                const unsigned int u_0 = fbits(r0[c]), u_1 = fbits(r1[c]);
                *(unsigned int*)(Bh + (bnn + c) * BSTR + bkk) =
                    (u_0 >> 16) | (u_1 & 0xffff0000u);
                const float h0 = tof(u_0 & 0xffff0000u), h1 = tof(u_1 & 0xffff0000u);
                const unsigned int l_0 = fbits(r0[c] - h0), l_1 = fbits(r1[c] - h1);
                *(unsigned int*)(Bl + (bnn + c) * BSTR + bkk) =
                    (l_0 >> 16) | (l_1 & 0xffff0000u);
            }
        }
        lds_barrier();                      // lgkm only — vm loads stay in flight

        // --- prefetch k0+64 into the just-freed regs (used 2 calls later) ---
        const int kp = k0 + 64;
        if (kp < KTOT) {
            aT = *(const float4*)((kp < NIN) ? pAin + kp : pAz + (kp - NIN));
            const float* bp = (kp < NIN) ? pBin + (size_t)kp * UNITS
                                         : pBrc + (size_t)(kp - NIN) * UNITS;
            c0a = *(const float4*)(bp);
            c0b = *(const float4*)(bp + 4);
            c1a = *(const float4*)(bp + UNITS);
            c1b = *(const float4*)(bp + UNITS + 4);
        }

        // --- fragments + MFMA (8 or 12 per wave) ---
        bf16x8 ah_, al_ = {};
        {
            const int off = (wm + lm) * BK + q * 8;
            ah_ = *(const bf16x8*)(Ah + off);              // ds_read_b128
            if (full) al_ = *(const bf16x8*)(Al + off);
        }
        bf16x8 bh_[4], bl_[4];
        #pragma unroll
        for (int j = 0; j < 4; ++j) {
            const int off = (wn + j * 16 + lm) * BSTR + q * 8;   // 8B aligned
            const uint2 ha = *(const uint2*)(Bh + off);
            const uint2 hb = *(const uint2*)(Bh + off + 4);
            const uint2 la = *(const uint2*)(Bl + off);
            const uint2 lb = *(const uint2*)(Bl + off + 4);
            uint4 hu = { ha.x, ha.y, hb.x, hb.y };
            uint4 lu = { la.x, la.y, lb.x, lb.y };
            bh_[j] = __builtin_bit_cast(bf16x8, hu);
            bl_[j] = __builtin_bit_cast(bf16x8, lu);
        }
        #pragma unroll
        for (int j = 0; j < 4; ++j) {
            acc[j] = __builtin_amdgcn_mfma_f32_16x16x32_bf16(ah_, bh_[j], acc[j], 0, 0, 0);
            acc[j] = __builtin_amdgcn_mfma_f32_16x16x32_bf16(ah_, bl_[j], acc[j], 0, 0, 0);
        }
        if (full) {
            #pragma unroll
            for (int j = 0; j < 4; ++j)
                acc[j] = __builtin_amdgcn_mfma_f32_16x16x32_bf16(al_, bh_[j], acc[j], 0, 0, 0);
        }

        lds_barrier();                      // protect LDS from next tile's stores
    };

    #pragma unroll 1
    for (int k0 = 0; k0 < KTOT; k0 += 64) {
        tile(aS0, s0b0a, s0b0b, s0b1a, s0b1b, k0);
        tile(aS1, s1b0a, s1b0b, s1b1a, s1b1b, k0 + 32);
    }

    // --- fused AdEx epilogue. C/D layout: col=lane&15, row=(lane>>4)*4+reg ---
    const size_t CH = (size_t)B_SZ * UNITS;
    float dgv[4];
    #pragma unroll
    for (int j = 0; j < 4; ++j) {
        const int n = bn0 + wn + j * 16 + lm;
        dgv[j] = Wrec[(size_t)n * UNITS + n];      // autapse diagonal
    }
    #pragma unroll
    for (int rr = 0; rr < 4; ++rr) {
        const int b = bm0 + wm + q * 4 + rr;
        const size_t rowb = (size_t)b * UNITS;
        #pragma unroll
        for (int j = 0; j < 4; ++j) {
            const int n = bn0 + wn + j * 16 + lm;
            const size_t idx = rowb + n;
            const float vv = v_in[idx];
            const float wv = w_in[idx];
            const float zv = zsp[idx];
            const int   rv = r_in[idx];
            const float it = acc[j][rr] - zv * dgv[j];
            float nv, nz, nw, nr;
            adex_one(it, vv, wv, zv, rv, nv, nz, nw, nr);
            out[idx]          = nv;
            out[CH + idx]     = nz;
            out[2 * CH + idx] = nw;
            out[3 * CH + idx] = nr;
        }
    }
}

// ---------------------------------------------------------------------------
// d_in order (setup_inputs dict): inputs, v, r(int32), w, z, input_weights, recurrent_weights
// ---------------------------------------------------------------------------
extern "C" void kernel_launch(void* const* d_in, const int* in_sizes, int n_in,
                              void* d_out, int out_size, void* d_ws, size_t ws_size,
                              hipStream_t stream) {
    (void)in_sizes; (void)n_in; (void)out_size; (void)d_ws; (void)ws_size;
    const float* inp  = (const float*)d_in[0];
    const float* v    = (const float*)d_in[1];
    const int*   r    = (const int*)d_in[2];
    const float* w    = (const float*)d_in[3];
    const float* z    = (const float*)d_in[4];
    const float* Win  = (const float*)d_in[5];
    const float* Wrec = (const float*)d_in[6];
    float* out = (float*)d_out;

    dim3 g(UNITS / BN, B_SZ / BM);   // (32, 16) = 512 blocks -> 2 per CU
    adex_fused<<<g, dim3(256), 0, stream>>>(inp, z, Win, Wrec, v, w, r, out);
}